// Round 11
// baseline (295.444 us; speedup 1.0000x reference)
//
#include <hip/hip_runtime.h>
#include <stdint.h>

// RandomMaskSubgraphs — round 11.
// vs round 10 (278 us): k_append was flush-write bound (33 B runs < 64 B line;
// WRITE 53 MB @ 0.9 TB/s). Changes:
//  - NB 1024->512 (RPB 79): flush runs ~66 B >= one line.
//  - k_enc fused into k_append (deg/alive ready; saves 22 MB reads + launch).
//  - dedup emits packed (row<<16)|col (same order as hash; cheaper decode).
// PRNG v0 (partitionable split + randint subkey split) bit-exact since r4.

#define NN 40000
#define SAMPN (NN / 2)
#define WORDS 1250               // col bitmap words (40000/32)
#define SWORDS 40                // summary words
#define NB 512                   // buckets
#define RPB 79                   // rows per bucket (512*79 >= 40000)
#define CAP 16384                // entries per bucket (mean ~11k)
#define CURSTRIDE 4
#define EPB 2816                 // edges per block in binned append (11*256)
#define NE (EPB / 256)           // 11 edges per thread
#define SELFPB 44                // self nodes per append block (910*44 >= 40000)
#define SCAP (3 * EPB + SELFPB)  // 8492 -> 34 KB

// ---------------- Threefry-2x32 (20 rounds, JAX schedule) ----------------
__host__ __device__ __forceinline__ void tf2x32(unsigned k0, unsigned k1,
                                                unsigned x0, unsigned x1,
                                                unsigned &o0, unsigned &o1) {
  unsigned ks2 = k0 ^ k1 ^ 0x1BD11BDAu;
  x0 += k0; x1 += k1;
#define TFR(r) { x0 += x1; x1 = (x1 << (r)) | (x1 >> (32 - (r))); x1 ^= x0; }
  TFR(13) TFR(15) TFR(26) TFR(6)
  x0 += k1;  x1 += ks2 + 1u;
  TFR(17) TFR(29) TFR(16) TFR(24)
  x0 += ks2; x1 += k0 + 2u;
  TFR(13) TFR(15) TFR(26) TFR(6)
  x0 += k0;  x1 += k1 + 3u;
  TFR(17) TFR(29) TFR(16) TFR(24)
  x0 += k1;  x1 += ks2 + 4u;
  TFR(13) TFR(15) TFR(26) TFR(6)
  x0 += ks2; x1 += k0 + 5u;
#undef TFR
  o0 = x0; o1 = x1;
}

// jax.random.randint element e with pre-split subkeys k1=(a,b), k2=(c,d)
__device__ __forceinline__ unsigned jrand(unsigned a, unsigned b, unsigned c,
                                          unsigned d, unsigned e, unsigned span) {
  unsigned x0, x1, y0, y1;
  tf2x32(a, b, 0u, e, x0, x1);
  unsigned hi = x0 ^ x1;
  tf2x32(c, d, 0u, e, y0, y1);
  unsigned lo = y0 ^ y1;
  unsigned mult = 65536u % span;
  mult = (mult * mult) % span;
  return ((hi % span) * mult + (lo % span)) % span;
}

// ---------------- init / BFS ----------------
__global__ void k_zero16(uint4 *p, int n16) {
  int i = blockIdx.x * blockDim.x + threadIdx.x;
  if (i < n16) p[i] = make_uint4(0u, 0u, 0u, 0u);
}
// fused: BFS seeds + random keep-node sampling (all writes set 1; order-free)
__global__ void k_seed_samp(const int *seeds, int ns, unsigned char *cur,
                            unsigned char *mask_bfs,
                            unsigned a, unsigned b, unsigned c, unsigned d) {
  int i = blockIdx.x * blockDim.x + threadIdx.x;
  if (i < ns) { int s = seeds[i]; cur[s] = 1; mask_bfs[s] = 1; }
  if (i < SAMPN) {
    unsigned idx = jrand(a, b, c, d, (unsigned)i, (unsigned)NN);
    mask_bfs[idx] = 1;
  }
}
__global__ void k_level0(const int *rows, const int *cols, int E,
                         const unsigned char *cur, unsigned char *alive,
                         unsigned char *touched, unsigned char *mask_bfs) {
  int e = blockIdx.x * blockDim.x + threadIdx.x;
  if (e >= E) return;
  int r = rows[e], c = cols[e];
  if (cur[r] | cur[c]) {
    alive[e] = 0;
    touched[r] = 1; touched[c] = 1;
    mask_bfs[r] = 1; mask_bfs[c] = 1;
  } else alive[e] = 1;
}
__global__ void k_level1_deg(const int *rows, const int *cols, int E,
                             const unsigned char *touched, unsigned char *alive,
                             int *deg) {
  int e = blockIdx.x * blockDim.x + threadIdx.x;
  if (e >= E) return;
  if (alive[e]) {
    int r = rows[e];
    if (touched[r] | touched[cols[e]]) alive[e] = 0;
    else atomicAdd(&deg[r], 1);
  }
}

// ---------------- mask compaction (ushort indices) ----------------
__global__ __launch_bounds__(1024) void k_scan_mask(const unsigned char *flags,
                                                    unsigned short *mask_idx,
                                                    int *tem_num) {
  __shared__ int wsum[16];
  const unsigned *f = (const unsigned *)flags; // 10000 uints
  int tid = threadIdx.x, lane = tid & 63, wid = tid >> 6;
  int base = tid * 10;
  unsigned u[10];
  int cnt = 0;
  for (int j = 0; j < 10; j++) {
    int i = base + j;
    u[j] = (i < 10000) ? f[i] : 0u;
    cnt += __popc(u[j]);
  }
  int x = cnt;
  for (int d = 1; d < 64; d <<= 1) {
    int y = __shfl_up(x, d, 64);
    if (lane >= d) x += y;
  }
  if (lane == 63) wsum[wid] = x;
  __syncthreads();
  if (wid == 0) {
    int v = (lane < 16) ? wsum[lane] : 0;
    int y = v;
    for (int d = 1; d < 16; d <<= 1) {
      int z = __shfl_up(y, d, 64);
      if (lane >= d) y += z;
    }
    if (lane < 16) wsum[lane] = y - v;
  }
  __syncthreads();
  int off = wsum[wid] + (x - cnt);
  for (int j = 0; j < 10; j++) {
    int i = base + j;
    unsigned v = u[j];
    while (v) {
      int byte = (__ffs(v) - 1) >> 3;
      v &= v - 1;
      mask_idx[off++] = (unsigned short)(i * 4 + byte);
    }
  }
  if (tid == 1023) *tem_num = off;
}

// ---------------- binned append (tem + alive + self) + fused encoder ----------
__global__ __launch_bounds__(256) void k_append(
    const int *rows, const int *cols, const unsigned char *alive,
    const int *deg, const unsigned short *mask_idx, const int *tem_num,
    int *cursors, unsigned *bucketmem, float *out,
    unsigned ra, unsigned rb, unsigned rc, unsigned rd,
    unsigned ca, unsigned cb, unsigned cc, unsigned cd, int E) {
  __shared__ unsigned sorted[SCAP];     // 34 KB
  __shared__ int cnt[NB];               // 2 KB
  __shared__ unsigned short ofs[NB];    // 1 KB
  __shared__ int ntot_s;
  int tid = threadIdx.x, lane = tid & 63, wid = tid >> 6;
  int e0 = blockIdx.x * EPB;
  int i0 = blockIdx.x * SELFPB;         // self-node range
  int i1 = i0 + SELFPB; if (i1 > NN) i1 = NN;
  unsigned span = (unsigned)*tem_num;
  const unsigned NOPE = 0xFFFFFFFFu;

  unsigned tval[NE], aval[NE];

  for (int i = tid; i < NB; i += 256) cnt[i] = 0;
  __syncthreads();
  // pass A: draw + gather once, count, cache in registers; fused encoder out
#pragma unroll
  for (int k = 0; k < NE; k++) {
    int e = e0 + k * 256 + tid;
    if (e < E) {
      unsigned iR = jrand(ra, rb, rc, rd, (unsigned)e, span);
      unsigned iC = jrand(ca, cb, cc, cd, (unsigned)e, span);
      unsigned tr = (unsigned)mask_idx[iR], tc = (unsigned)mask_idx[iC];
      tval[k] = (tr << 16) | tc;
      atomicAdd(&cnt[tr / RPB], 1);
      atomicAdd(&cnt[tc / RPB], 1);
      int r = rows[e], c = cols[e];
      float v = 0.0f;
      if (alive[e]) {
        aval[k] = ((unsigned)r << 16) | (unsigned)c;
        atomicAdd(&cnt[(unsigned)r / RPB], 1);
        float xr = (float)deg[r] + 1e-12f;
        float xc = (float)deg[c] + 1e-12f;
        float dr = (float)(1.0 / sqrt((double)xr));
        float dc = (float)(1.0 / sqrt((double)xc));
        v = dr * dc;
      } else aval[k] = NOPE;
      out[e] = (float)r;
      out[E + e] = (float)c;
      out[2 * E + e] = v;
    } else { tval[k] = NOPE; aval[k] = NOPE; }
  }
  for (int i = i0 + tid; i < i1; i += 256) atomicAdd(&cnt[i / RPB], 1);
  __syncthreads();
  // exclusive scan of cnt[512] by wave 0 -> ofs (ushort)
  if (wid == 0) {
    int carry = 0;
    for (int c8 = 0; c8 < NB / 64; c8++) {
      int v = cnt[c8 * 64 + lane];
      int x = v;
      for (int d = 1; d < 64; d <<= 1) {
        int y = __shfl_up(x, d, 64);
        if (lane >= d) x += y;
      }
      ofs[c8 * 64 + lane] = (unsigned short)(carry + x - v);
      carry += __shfl(x, 63, 64);
    }
    if (lane == 0) ntot_s = carry;
  }
  __syncthreads();
  for (int i = tid; i < NB; i += 256) cnt[i] = ofs[i];
  __syncthreads();
  // pass B: scatter from registers (+ self)
#pragma unroll
  for (int k = 0; k < NE; k++) {
    unsigned v = tval[k];
    if (v != NOPE) {
      unsigned tr = v >> 16, tc = v & 0xFFFFu;
      int p1 = atomicAdd(&cnt[tr / RPB], 1);
      sorted[p1] = v;
      int p2 = atomicAdd(&cnt[tc / RPB], 1);
      sorted[p2] = (tc << 16) | tr;
      unsigned a = aval[k];
      if (a != NOPE) {
        int p3 = atomicAdd(&cnt[(a >> 16) / RPB], 1);
        sorted[p3] = a;
      }
    }
  }
  for (int i = i0 + tid; i < i1; i += 256) {
    int p = atomicAdd(&cnt[i / RPB], 1);
    sorted[p] = ((unsigned)i << 16) | (unsigned)i;
  }
  __syncthreads();
  // reserve global space: one atomicAdd per bucket per block
  int ntot = ntot_s;
  for (int b = tid; b < NB; b += 256) {
    int end = (b < NB - 1) ? (int)ofs[b + 1] : ntot;
    int len = end - (int)ofs[b];
    cnt[b] = len ? atomicAdd(&cursors[b * CURSTRIDE], len) : 0;
  }
  __syncthreads();
  // coalesced flush (store local row id in high 16)
  for (int j = tid; j < ntot; j += 256) {
    unsigned item = sorted[j];
    unsigned r = item >> 16;
    unsigned b = r / RPB;
    unsigned lr = r - b * RPB;
    int idx = cnt[b] + (j - (int)ofs[b]);
    if (idx < CAP) bucketmem[b * CAP + idx] = (lr << 16) | (item & 0xFFFFu);
  }
}

// ---------------- dedup: wave-per-row + summary bitmap ----------------
__global__ __launch_bounds__(256) void k_dedup(unsigned *bucketmem,
                                               const int *cursors, int *uniq_cnt) {
  int b = blockIdx.x;
  int rowbase = b * RPB;
  if (rowbase >= NN) { if (threadIdx.x == 0) uniq_cnt[b] = 0; return; }

  __shared__ unsigned short arr[CAP];  // 32 KB
  __shared__ int cnt[RPB];
  __shared__ int rowend[RPB];
  __shared__ int curs[RPB];
  __shared__ int rowoff[RPB];
  __shared__ unsigned bm[4][WORDS];    // 20 KB wave-private bitmaps
  __shared__ unsigned sm[4][SWORDS];

  int tid = threadIdx.x, lane = tid & 63, wid = tid >> 6;
  int n = cursors[b * CURSTRIDE]; if (n > CAP) n = CAP;
  const unsigned *src = bucketmem + (size_t)b * CAP;

  for (int i = tid; i < RPB; i += 256) cnt[i] = 0;
  __syncthreads();
  for (int j = tid; j < n; j += 256) atomicAdd(&cnt[src[j] >> 16], 1);
  __syncthreads();
  if (tid == 0) {
    int s = 0;
    for (int r = 0; r < RPB; r++) { curs[r] = s; s += cnt[r]; rowend[r] = s; }
  }
  __syncthreads();
  for (int j = tid; j < n; j += 256) {
    unsigned v = src[j];
    int p = atomicAdd(&curs[v >> 16], 1);
    arr[p] = (unsigned short)v;
  }
  for (int w = lane; w < WORDS; w += 64) bm[wid][w] = 0u;
  if (lane < SWORDS) sm[wid][lane] = 0u;
  __syncthreads();

  for (int r = wid; r < RPB; r += 4) {
    int s1 = rowend[r], s0 = s1 - cnt[r];
    for (int j = s0 + lane; j < s1; j += 64) {
      unsigned c = arr[j];
      atomicOr(&bm[wid][c >> 5], 1u << (c & 31));
      atomicOr(&sm[wid][c >> 10], 1u << ((c >> 5) & 31));
    }
    unsigned s = (lane < SWORDS) ? sm[wid][lane] : 0u;
    int m = 0;
    unsigned t = s;
    while (t) {
      int w = (lane << 5) + (__ffs(t) - 1);
      t &= t - 1;
      m += __popc(bm[wid][w]);
    }
    int x = m;
    for (int d = 1; d < 64; d <<= 1) {
      int y = __shfl_up(x, d, 64);
      if (lane >= d) x += y;
    }
    int u = __shfl(x, 63, 64);
    int pos = s0 + (x - m);
    t = s;
    while (t) {
      int w = (lane << 5) + (__ffs(t) - 1);
      t &= t - 1;
      unsigned mm = bm[wid][w];
      bm[wid][w] = 0u;
      while (mm) {
        int bit = __ffs(mm) - 1;
        mm &= mm - 1;
        arr[pos++] = (unsigned short)((w << 5) + bit);
      }
    }
    if (lane < SWORDS) sm[wid][lane] = 0u;
    if (lane == 0) cnt[r] = u;
  }
  __syncthreads();
  if (tid == 0) {
    int s = 0;
    for (int r = 0; r < RPB; r++) { rowoff[r] = s; s += cnt[r]; }
    uniq_cnt[b] = s;
  }
  __syncthreads();
  // write uniques as packed (row<<16)|col — ascending == hash order
  unsigned *dst = bucketmem + (size_t)b * CAP;
  for (int r = wid; r < RPB; r += 4) {
    int s0 = r ? rowend[r - 1] : 0;
    int u = cnt[r], o = rowoff[r];
    unsigned rowpack = (unsigned)(rowbase + r) << 16;
    for (int j = lane; j < u; j += 64)
      dst[o + j] = rowpack | (unsigned)arr[s0 + j];
  }
}

// ---------------- emit (fused offset-reduction + diag) ----------------
__global__ __launch_bounds__(256) void k_emit(const unsigned *bucketmem,
                                              const int *uniq_cnt, float *out,
                                              int E, int U) {
  __shared__ int part[4];
  int b = blockIdx.x;
  int tid = threadIdx.x, lane = tid & 63, wid = tid >> 6;
  // ob = sum of uniq_cnt[0..b) via masked butterfly reduction
  int acc = 0;
  for (int i = tid; i < NB; i += 256)
    if (i < b) acc += uniq_cnt[i];
  for (int d = 1; d < 64; d <<= 1) acc += __shfl_xor(acc, d, 64);
  if (lane == 0) part[wid] = acc;
  __syncthreads();
  int ob = part[0] + part[1] + part[2] + part[3];
  int ub = uniq_cnt[b];
  const unsigned *src = bucketmem + (size_t)b * CAP;
  int base3 = 3 * E;
  for (int j = tid; j < ub; j += 256) {
    unsigned h = src[j];
    unsigned r = h >> 16;
    unsigned c = h & 0xFFFFu;
    int idx = ob + j;
    if (idx < U) {
      out[base3 + idx] = (float)r;
      out[base3 + U + idx] = (float)c;
      out[base3 + 2 * U + idx] = 1.0f;
    }
  }
  if (b == NB - 1 && tid == 0) {
    int C = ob + ub;
    if (C != U) {
      int d = C - U; if (d < 0) d = -d; if (d > 60000) d = 60000;
      out[base3] = (float)(300000 + d); // sentinel (should never fire)
    }
  }
}

// ---------------- launch ----------------
extern "C" void kernel_launch(void *const *d_in, const int *in_sizes, int n_in,
                              void *d_out, int out_size, void *d_ws,
                              size_t ws_size, hipStream_t stream) {
  const int *rows = (const int *)d_in[0];
  const int *cols = (const int *)d_in[1];
  const int *seeds = (const int *)d_in[3];
  const int E = in_sizes[0];
  const int ns = in_sizes[3];
  float *out = (float *)d_out;
  const int U = (out_size - 3 * E) / 3;

  // ---- workspace carve: zeroed region first, rest after ----
  int *I = (int *)d_ws;
  int *deg = I;      I += NN;               // zeroed
  int *cursors = I;  I += NB * CURSTRIDE;   // zeroed
  int *uniq_cnt = I; I += NB;               // zeroed
  unsigned char *cur = (unsigned char *)I;  // 3*NN bytes zeroed
  unsigned char *touched = cur + NN;
  unsigned char *mask_bfs = touched + NN;
  size_t zero_bytes = (size_t)((char *)(mask_bfs + NN) - (char *)deg);
  int *J = (int *)(mask_bfs + NN);
  int *tem_num = J;  J += 1;
  J += 1; // pad to 8B
  unsigned short *mask_idx = (unsigned short *)J;
  J += NN / 2; // 40000 ushorts = 20000 ints
  unsigned *bucketmem = (unsigned *)J; J += (size_t)NB * CAP; // 32 MB
  unsigned char *alive = (unsigned char *)J; // E bytes (fully written)

  // ---- host key derivation (v0): key(1)=(0,1); split(3); randint split(2) ----
  unsigned F[3][2];
  tf2x32(0u, 1u, 0u, 0u, F[0][0], F[0][1]); // kS
  tf2x32(0u, 1u, 0u, 1u, F[1][0], F[1][1]); // kR
  tf2x32(0u, 1u, 0u, 2u, F[2][0], F[2][1]); // kC
  unsigned K[3][4];
  for (int s = 0; s < 3; s++) {
    tf2x32(F[s][0], F[s][1], 0u, 0u, K[s][0], K[s][1]); // k1 (higher bits)
    tf2x32(F[s][0], F[s][1], 0u, 1u, K[s][2], K[s][3]); // k2 (lower bits)
  }

  dim3 b(256);
  int gE = (E + 255) / 256;
  int gSS = (SAMPN + 255) / 256; // covers ns=2000 too
  int gT = (E + EPB - 1) / EPB;  // 910; also covers self nodes (910*44>=NN)
  int n16 = (int)(zero_bytes / 16);

  k_zero16<<<(n16 + 255) / 256, b, 0, stream>>>((uint4 *)deg, n16);
  k_seed_samp<<<gSS, b, 0, stream>>>(seeds, ns, cur, mask_bfs,
                                     K[0][0], K[0][1], K[0][2], K[0][3]);
  k_level0<<<gE, b, 0, stream>>>(rows, cols, E, cur, alive, touched, mask_bfs);
  k_level1_deg<<<gE, b, 0, stream>>>(rows, cols, E, touched, alive, deg);
  k_scan_mask<<<1, 1024, 0, stream>>>(mask_bfs, mask_idx, tem_num);
  k_append<<<gT, b, 0, stream>>>(rows, cols, alive, deg, mask_idx, tem_num,
                                 cursors, bucketmem, out,
                                 K[1][0], K[1][1], K[1][2], K[1][3],
                                 K[2][0], K[2][1], K[2][2], K[2][3], E);
  k_dedup<<<NB, b, 0, stream>>>(bucketmem, cursors, uniq_cnt);
  k_emit<<<NB, b, 0, stream>>>(bucketmem, uniq_cnt, out, E, U);
}

// Round 12
// 289.460 us; speedup vs baseline: 1.0207x; 1.0207x over previous
//
#include <hip/hip_runtime.h>
#include <stdint.h>

// RandomMaskSubgraphs — round 12.
// r11 regression root-cause: NB=512 doubled k_dedup's arr (LDS 54.8 KB -> 2
// blocks/CU). Fix: decouple — append keeps NB=512 bins (flush-friendly);
// dedup/emit run 1024 half-bucket blocks (rows 0-39 / 40-78 of each bucket),
// arr back to 16 KB -> ~39 KB LDS -> 4 blocks/CU. Order (bucket,half,row) ==
// row order, so unique ordering is preserved.
// PRNG v0 (partitionable split + randint subkey split) bit-exact since r4.

#define NN 40000
#define SAMPN (NN / 2)
#define WORDS 1250               // col bitmap words (40000/32)
#define SWORDS 40                // summary words
#define NB 512                   // append buckets
#define RPB 79                   // rows per bucket (512*79 >= 40000)
#define HR 40                    // rows per dedup half-block
#define NBD (2 * NB)             // dedup/emit blocks
#define CAP 16384                // entries per bucket (mean ~11k)
#define HCAP (CAP / 2)           // unique capacity per half
#define CURSTRIDE 4
#define EPB 2816                 // edges per block in binned append (11*256)
#define NE (EPB / 256)           // 11 edges per thread
#define SELFPB 44                // self nodes per append block (910*44 >= 40000)
#define SCAP (3 * EPB + SELFPB)  // 8492 -> 34 KB

// ---------------- Threefry-2x32 (20 rounds, JAX schedule) ----------------
__host__ __device__ __forceinline__ void tf2x32(unsigned k0, unsigned k1,
                                                unsigned x0, unsigned x1,
                                                unsigned &o0, unsigned &o1) {
  unsigned ks2 = k0 ^ k1 ^ 0x1BD11BDAu;
  x0 += k0; x1 += k1;
#define TFR(r) { x0 += x1; x1 = (x1 << (r)) | (x1 >> (32 - (r))); x1 ^= x0; }
  TFR(13) TFR(15) TFR(26) TFR(6)
  x0 += k1;  x1 += ks2 + 1u;
  TFR(17) TFR(29) TFR(16) TFR(24)
  x0 += ks2; x1 += k0 + 2u;
  TFR(13) TFR(15) TFR(26) TFR(6)
  x0 += k0;  x1 += k1 + 3u;
  TFR(17) TFR(29) TFR(16) TFR(24)
  x0 += k1;  x1 += ks2 + 4u;
  TFR(13) TFR(15) TFR(26) TFR(6)
  x0 += ks2; x1 += k0 + 5u;
#undef TFR
  o0 = x0; o1 = x1;
}

// jax.random.randint element e with pre-split subkeys k1=(a,b), k2=(c,d)
__device__ __forceinline__ unsigned jrand(unsigned a, unsigned b, unsigned c,
                                          unsigned d, unsigned e, unsigned span) {
  unsigned x0, x1, y0, y1;
  tf2x32(a, b, 0u, e, x0, x1);
  unsigned hi = x0 ^ x1;
  tf2x32(c, d, 0u, e, y0, y1);
  unsigned lo = y0 ^ y1;
  unsigned mult = 65536u % span;
  mult = (mult * mult) % span;
  return ((hi % span) * mult + (lo % span)) % span;
}

// ---------------- init / BFS ----------------
__global__ void k_zero16(uint4 *p, int n16) {
  int i = blockIdx.x * blockDim.x + threadIdx.x;
  if (i < n16) p[i] = make_uint4(0u, 0u, 0u, 0u);
}
__global__ void k_seed_samp(const int *seeds, int ns, unsigned char *cur,
                            unsigned char *mask_bfs,
                            unsigned a, unsigned b, unsigned c, unsigned d) {
  int i = blockIdx.x * blockDim.x + threadIdx.x;
  if (i < ns) { int s = seeds[i]; cur[s] = 1; mask_bfs[s] = 1; }
  if (i < SAMPN) {
    unsigned idx = jrand(a, b, c, d, (unsigned)i, (unsigned)NN);
    mask_bfs[idx] = 1;
  }
}
__global__ void k_level0(const int *rows, const int *cols, int E,
                         const unsigned char *cur, unsigned char *alive,
                         unsigned char *touched, unsigned char *mask_bfs) {
  int e = blockIdx.x * blockDim.x + threadIdx.x;
  if (e >= E) return;
  int r = rows[e], c = cols[e];
  if (cur[r] | cur[c]) {
    alive[e] = 0;
    touched[r] = 1; touched[c] = 1;
    mask_bfs[r] = 1; mask_bfs[c] = 1;
  } else alive[e] = 1;
}
__global__ void k_level1_deg(const int *rows, const int *cols, int E,
                             const unsigned char *touched, unsigned char *alive,
                             int *deg) {
  int e = blockIdx.x * blockDim.x + threadIdx.x;
  if (e >= E) return;
  if (alive[e]) {
    int r = rows[e];
    if (touched[r] | touched[cols[e]]) alive[e] = 0;
    else atomicAdd(&deg[r], 1);
  }
}

// ---------------- mask compaction (ushort indices) ----------------
__global__ __launch_bounds__(1024) void k_scan_mask(const unsigned char *flags,
                                                    unsigned short *mask_idx,
                                                    int *tem_num) {
  __shared__ int wsum[16];
  const unsigned *f = (const unsigned *)flags; // 10000 uints
  int tid = threadIdx.x, lane = tid & 63, wid = tid >> 6;
  int base = tid * 10;
  unsigned u[10];
  int cnt = 0;
  for (int j = 0; j < 10; j++) {
    int i = base + j;
    u[j] = (i < 10000) ? f[i] : 0u;
    cnt += __popc(u[j]);
  }
  int x = cnt;
  for (int d = 1; d < 64; d <<= 1) {
    int y = __shfl_up(x, d, 64);
    if (lane >= d) x += y;
  }
  if (lane == 63) wsum[wid] = x;
  __syncthreads();
  if (wid == 0) {
    int v = (lane < 16) ? wsum[lane] : 0;
    int y = v;
    for (int d = 1; d < 16; d <<= 1) {
      int z = __shfl_up(y, d, 64);
      if (lane >= d) y += z;
    }
    if (lane < 16) wsum[lane] = y - v;
  }
  __syncthreads();
  int off = wsum[wid] + (x - cnt);
  for (int j = 0; j < 10; j++) {
    int i = base + j;
    unsigned v = u[j];
    while (v) {
      int byte = (__ffs(v) - 1) >> 3;
      v &= v - 1;
      mask_idx[off++] = (unsigned short)(i * 4 + byte);
    }
  }
  if (tid == 1023) *tem_num = off;
}

// ---------------- binned append (tem + alive + self) + fused encoder ----------
__global__ __launch_bounds__(256) void k_append(
    const int *rows, const int *cols, const unsigned char *alive,
    const int *deg, const unsigned short *mask_idx, const int *tem_num,
    int *cursors, unsigned *bucketmem, float *out,
    unsigned ra, unsigned rb, unsigned rc, unsigned rd,
    unsigned ca, unsigned cb, unsigned cc, unsigned cd, int E) {
  __shared__ unsigned sorted[SCAP];     // 34 KB
  __shared__ int cnt[NB];               // 2 KB
  __shared__ unsigned short ofs[NB];    // 1 KB
  __shared__ int ntot_s;
  int tid = threadIdx.x, lane = tid & 63, wid = tid >> 6;
  int e0 = blockIdx.x * EPB;
  int i0 = blockIdx.x * SELFPB;         // self-node range
  int i1 = i0 + SELFPB; if (i1 > NN) i1 = NN;
  unsigned span = (unsigned)*tem_num;
  const unsigned NOPE = 0xFFFFFFFFu;

  unsigned tval[NE], aval[NE];

  for (int i = tid; i < NB; i += 256) cnt[i] = 0;
  __syncthreads();
  // pass A: draw + gather once, count, cache in registers; fused encoder out
#pragma unroll
  for (int k = 0; k < NE; k++) {
    int e = e0 + k * 256 + tid;
    if (e < E) {
      unsigned iR = jrand(ra, rb, rc, rd, (unsigned)e, span);
      unsigned iC = jrand(ca, cb, cc, cd, (unsigned)e, span);
      unsigned tr = (unsigned)mask_idx[iR], tc = (unsigned)mask_idx[iC];
      tval[k] = (tr << 16) | tc;
      atomicAdd(&cnt[tr / RPB], 1);
      atomicAdd(&cnt[tc / RPB], 1);
      int r = rows[e], c = cols[e];
      float v = 0.0f;
      if (alive[e]) {
        aval[k] = ((unsigned)r << 16) | (unsigned)c;
        atomicAdd(&cnt[(unsigned)r / RPB], 1);
        float xr = (float)deg[r] + 1e-12f;
        float xc = (float)deg[c] + 1e-12f;
        float dr = (float)(1.0 / sqrt((double)xr));
        float dc = (float)(1.0 / sqrt((double)xc));
        v = dr * dc;
      } else aval[k] = NOPE;
      out[e] = (float)r;
      out[E + e] = (float)c;
      out[2 * E + e] = v;
    } else { tval[k] = NOPE; aval[k] = NOPE; }
  }
  for (int i = i0 + tid; i < i1; i += 256) atomicAdd(&cnt[i / RPB], 1);
  __syncthreads();
  // exclusive scan of cnt[512] by wave 0 -> ofs (ushort)
  if (wid == 0) {
    int carry = 0;
    for (int c8 = 0; c8 < NB / 64; c8++) {
      int v = cnt[c8 * 64 + lane];
      int x = v;
      for (int d = 1; d < 64; d <<= 1) {
        int y = __shfl_up(x, d, 64);
        if (lane >= d) x += y;
      }
      ofs[c8 * 64 + lane] = (unsigned short)(carry + x - v);
      carry += __shfl(x, 63, 64);
    }
    if (lane == 0) ntot_s = carry;
  }
  __syncthreads();
  for (int i = tid; i < NB; i += 256) cnt[i] = ofs[i];
  __syncthreads();
  // pass B: scatter from registers (+ self)
#pragma unroll
  for (int k = 0; k < NE; k++) {
    unsigned v = tval[k];
    if (v != NOPE) {
      unsigned tr = v >> 16, tc = v & 0xFFFFu;
      int p1 = atomicAdd(&cnt[tr / RPB], 1);
      sorted[p1] = v;
      int p2 = atomicAdd(&cnt[tc / RPB], 1);
      sorted[p2] = (tc << 16) | tr;
      unsigned a = aval[k];
      if (a != NOPE) {
        int p3 = atomicAdd(&cnt[(a >> 16) / RPB], 1);
        sorted[p3] = a;
      }
    }
  }
  for (int i = i0 + tid; i < i1; i += 256) {
    int p = atomicAdd(&cnt[i / RPB], 1);
    sorted[p] = ((unsigned)i << 16) | (unsigned)i;
  }
  __syncthreads();
  // reserve global space: one atomicAdd per bucket per block
  int ntot = ntot_s;
  for (int b = tid; b < NB; b += 256) {
    int end = (b < NB - 1) ? (int)ofs[b + 1] : ntot;
    int len = end - (int)ofs[b];
    cnt[b] = len ? atomicAdd(&cursors[b * CURSTRIDE], len) : 0;
  }
  __syncthreads();
  // coalesced flush (store local row id in high 16)
  for (int j = tid; j < ntot; j += 256) {
    unsigned item = sorted[j];
    unsigned r = item >> 16;
    unsigned b = r / RPB;
    unsigned lr = r - b * RPB;
    int idx = cnt[b] + (j - (int)ofs[b]);
    if (idx < CAP) bucketmem[b * CAP + idx] = (lr << 16) | (item & 0xFFFFu);
  }
}

// ---------------- dedup: half-bucket blocks, wave-per-row + summary bitmap ----
__global__ __launch_bounds__(256) void k_dedup(unsigned *bucketmem,
                                               const int *cursors, int *uniq_cnt) {
  int blk = blockIdx.x;
  int b = blk >> 1, h = blk & 1;
  int rowbase = b * RPB;
  int lr0 = h * HR;                       // local row range [lr0, lr0+nh)
  int nh = RPB - lr0; if (nh > HR) nh = HR;
  int remain = NN - rowbase - lr0;        // rows actually existing
  if (remain < nh) nh = remain;
  if (nh <= 0) { if (threadIdx.x == 0) uniq_cnt[blk] = 0; return; }

  __shared__ unsigned short arr[HCAP];  // 16 KB (half-bucket cols)
  __shared__ int cnt[HR];
  __shared__ int rowend[HR];
  __shared__ int curs[HR];
  __shared__ int rowoff[HR];
  __shared__ unsigned bm[4][WORDS];     // 20 KB wave-private bitmaps
  __shared__ unsigned sm[4][SWORDS];

  int tid = threadIdx.x, lane = tid & 63, wid = tid >> 6;
  int n = cursors[b * CURSTRIDE]; if (n > CAP) n = CAP;
  const unsigned *src = bucketmem + (size_t)b * CAP;

  for (int i = tid; i < nh; i += 256) cnt[i] = 0;
  __syncthreads();
  // count only rows in our half
  for (int j = tid; j < n; j += 256) {
    int lr = (int)(src[j] >> 16) - lr0;
    if ((unsigned)lr < (unsigned)nh) atomicAdd(&cnt[lr], 1);
  }
  __syncthreads();
  if (tid == 0) {
    int s = 0;
    for (int r = 0; r < nh; r++) { curs[r] = s; s += cnt[r]; rowend[r] = s; }
  }
  __syncthreads();
  for (int j = tid; j < n; j += 256) {
    unsigned v = src[j];
    int lr = (int)(v >> 16) - lr0;
    if ((unsigned)lr < (unsigned)nh) {
      int p = atomicAdd(&curs[lr], 1);
      arr[p] = (unsigned short)v;
    }
  }
  for (int w = lane; w < WORDS; w += 64) bm[wid][w] = 0u;
  if (lane < SWORDS) sm[wid][lane] = 0u;
  __syncthreads();

  for (int r = wid; r < nh; r += 4) {
    int s1 = rowend[r], s0 = s1 - cnt[r];
    for (int j = s0 + lane; j < s1; j += 64) {
      unsigned c = arr[j];
      atomicOr(&bm[wid][c >> 5], 1u << (c & 31));
      atomicOr(&sm[wid][c >> 10], 1u << ((c >> 5) & 31));
    }
    unsigned s = (lane < SWORDS) ? sm[wid][lane] : 0u;
    int m = 0;
    unsigned t = s;
    while (t) {
      int w = (lane << 5) + (__ffs(t) - 1);
      t &= t - 1;
      m += __popc(bm[wid][w]);
    }
    int x = m;
    for (int d = 1; d < 64; d <<= 1) {
      int y = __shfl_up(x, d, 64);
      if (lane >= d) x += y;
    }
    int u = __shfl(x, 63, 64);
    int pos = s0 + (x - m);
    t = s;
    while (t) {
      int w = (lane << 5) + (__ffs(t) - 1);
      t &= t - 1;
      unsigned mm = bm[wid][w];
      bm[wid][w] = 0u;
      while (mm) {
        int bit = __ffs(mm) - 1;
        mm &= mm - 1;
        arr[pos++] = (unsigned short)((w << 5) + bit);
      }
    }
    if (lane < SWORDS) sm[wid][lane] = 0u;
    if (lane == 0) cnt[r] = u;
  }
  __syncthreads();
  if (tid == 0) {
    int s = 0;
    for (int r = 0; r < nh; r++) { rowoff[r] = s; s += cnt[r]; }
    uniq_cnt[blk] = s;
  }
  __syncthreads();
  // write uniques as packed (row<<16)|col into the half's region
  unsigned *dst = bucketmem + (size_t)b * CAP + (size_t)h * HCAP;
  for (int r = wid; r < nh; r += 4) {
    int s0 = r ? rowend[r - 1] : 0;
    int u = cnt[r], o = rowoff[r];
    unsigned rowpack = (unsigned)(rowbase + lr0 + r) << 16;
    for (int j = lane; j < u; j += 64)
      dst[o + j] = rowpack | (unsigned)arr[s0 + j];
  }
}

// ---------------- emit (fused offset-reduction + diag) ----------------
__global__ __launch_bounds__(256) void k_emit(const unsigned *bucketmem,
                                              const int *uniq_cnt, float *out,
                                              int E, int U) {
  __shared__ int part[4];
  int blk = blockIdx.x;
  int tid = threadIdx.x, lane = tid & 63, wid = tid >> 6;
  // ob = sum of uniq_cnt[0..blk) via masked butterfly reduction
  int acc = 0;
  for (int i = tid; i < NBD; i += 256)
    if (i < blk) acc += uniq_cnt[i];
  for (int d = 1; d < 64; d <<= 1) acc += __shfl_xor(acc, d, 64);
  if (lane == 0) part[wid] = acc;
  __syncthreads();
  int ob = part[0] + part[1] + part[2] + part[3];
  int ub = uniq_cnt[blk];
  const unsigned *src = bucketmem + (size_t)(blk >> 1) * CAP
                        + (size_t)(blk & 1) * HCAP;
  int base3 = 3 * E;
  for (int j = tid; j < ub; j += 256) {
    unsigned h = src[j];
    unsigned r = h >> 16;
    unsigned c = h & 0xFFFFu;
    int idx = ob + j;
    if (idx < U) {
      out[base3 + idx] = (float)r;
      out[base3 + U + idx] = (float)c;
      out[base3 + 2 * U + idx] = 1.0f;
    }
  }
  if (blk == NBD - 1 && tid == 0) {
    int C = ob + ub;
    if (C != U) {
      int d = C - U; if (d < 0) d = -d; if (d > 60000) d = 60000;
      out[base3] = (float)(300000 + d); // sentinel (should never fire)
    }
  }
}

// ---------------- launch ----------------
extern "C" void kernel_launch(void *const *d_in, const int *in_sizes, int n_in,
                              void *d_out, int out_size, void *d_ws,
                              size_t ws_size, hipStream_t stream) {
  const int *rows = (const int *)d_in[0];
  const int *cols = (const int *)d_in[1];
  const int *seeds = (const int *)d_in[3];
  const int E = in_sizes[0];
  const int ns = in_sizes[3];
  float *out = (float *)d_out;
  const int U = (out_size - 3 * E) / 3;

  // ---- workspace carve: zeroed region first, rest after ----
  int *I = (int *)d_ws;
  int *deg = I;      I += NN;               // zeroed
  int *cursors = I;  I += NB * CURSTRIDE;   // zeroed
  int *uniq_cnt = I; I += NBD;              // zeroed
  unsigned char *cur = (unsigned char *)I;  // 3*NN bytes zeroed
  unsigned char *touched = cur + NN;
  unsigned char *mask_bfs = touched + NN;
  size_t zero_bytes = (size_t)((char *)(mask_bfs + NN) - (char *)deg);
  int *J = (int *)(mask_bfs + NN);
  int *tem_num = J;  J += 1;
  J += 1; // pad to 8B
  unsigned short *mask_idx = (unsigned short *)J;
  J += NN / 2; // 40000 ushorts = 20000 ints
  unsigned *bucketmem = (unsigned *)J; J += (size_t)NB * CAP; // 32 MB
  unsigned char *alive = (unsigned char *)J; // E bytes (fully written)

  // ---- host key derivation (v0): key(1)=(0,1); split(3); randint split(2) ----
  unsigned F[3][2];
  tf2x32(0u, 1u, 0u, 0u, F[0][0], F[0][1]); // kS
  tf2x32(0u, 1u, 0u, 1u, F[1][0], F[1][1]); // kR
  tf2x32(0u, 1u, 0u, 2u, F[2][0], F[2][1]); // kC
  unsigned K[3][4];
  for (int s = 0; s < 3; s++) {
    tf2x32(F[s][0], F[s][1], 0u, 0u, K[s][0], K[s][1]); // k1 (higher bits)
    tf2x32(F[s][0], F[s][1], 0u, 1u, K[s][2], K[s][3]); // k2 (lower bits)
  }

  dim3 b(256);
  int gE = (E + 255) / 256;
  int gSS = (SAMPN + 255) / 256; // covers ns=2000 too
  int gT = (E + EPB - 1) / EPB;  // 910; also covers self nodes (910*44>=NN)
  int n16 = (int)(zero_bytes / 16);

  k_zero16<<<(n16 + 255) / 256, b, 0, stream>>>((uint4 *)deg, n16);
  k_seed_samp<<<gSS, b, 0, stream>>>(seeds, ns, cur, mask_bfs,
                                     K[0][0], K[0][1], K[0][2], K[0][3]);
  k_level0<<<gE, b, 0, stream>>>(rows, cols, E, cur, alive, touched, mask_bfs);
  k_level1_deg<<<gE, b, 0, stream>>>(rows, cols, E, touched, alive, deg);
  k_scan_mask<<<1, 1024, 0, stream>>>(mask_bfs, mask_idx, tem_num);
  k_append<<<gT, b, 0, stream>>>(rows, cols, alive, deg, mask_idx, tem_num,
                                 cursors, bucketmem, out,
                                 K[1][0], K[1][1], K[1][2], K[1][3],
                                 K[2][0], K[2][1], K[2][2], K[2][3], E);
  k_dedup<<<NBD, b, 0, stream>>>(bucketmem, cursors, uniq_cnt);
  k_emit<<<NBD, b, 0, stream>>>(bucketmem, uniq_cnt, out, E, U);
}

// Round 13
// 269.616 us; speedup vs baseline: 1.0958x; 1.0736x over previous
//
#include <hip/hip_runtime.h>
#include <stdint.h>

// RandomMaskSubgraphs — round 13: combine proven-best pieces.
// r10 layout (NB=1024 everywhere; single-read dedup, 37 KB LDS, 4 blocks/CU)
// + r12 wins (enc fused into k_append; packed (row<<16)|col dedup output).
// k_dedup is LDS-atomic-throughput bound (~4 atomics/item); r11/r12's NB=512
// variants added double-reads / latency exposure for no atomic reduction.
// PRNG v0 (partitionable split + randint subkey split) bit-exact since r4.

#define NN 40000
#define SAMPN (NN / 2)
#define WORDS 1250               // col bitmap words (40000/32)
#define SWORDS 40                // summary words
#define NB 1024                  // buckets (append bins == dedup blocks)
#define RPB 40                   // rows per bucket (1024*40 >= 40000)
#define CAP 8192                 // entries per bucket (mean ~5.3k)
#define CURSTRIDE 4
#define EPB 2816                 // edges per block in binned append (11*256)
#define NE (EPB / 256)           // 11 edges per thread
#define SELFPB 44                // self nodes per append block (910*44 >= 40000)
#define SCAP (3 * EPB + SELFPB)  // 8492 -> 34 KB

// ---------------- Threefry-2x32 (20 rounds, JAX schedule) ----------------
__host__ __device__ __forceinline__ void tf2x32(unsigned k0, unsigned k1,
                                                unsigned x0, unsigned x1,
                                                unsigned &o0, unsigned &o1) {
  unsigned ks2 = k0 ^ k1 ^ 0x1BD11BDAu;
  x0 += k0; x1 += k1;
#define TFR(r) { x0 += x1; x1 = (x1 << (r)) | (x1 >> (32 - (r))); x1 ^= x0; }
  TFR(13) TFR(15) TFR(26) TFR(6)
  x0 += k1;  x1 += ks2 + 1u;
  TFR(17) TFR(29) TFR(16) TFR(24)
  x0 += ks2; x1 += k0 + 2u;
  TFR(13) TFR(15) TFR(26) TFR(6)
  x0 += k0;  x1 += k1 + 3u;
  TFR(17) TFR(29) TFR(16) TFR(24)
  x0 += k1;  x1 += ks2 + 4u;
  TFR(13) TFR(15) TFR(26) TFR(6)
  x0 += ks2; x1 += k0 + 5u;
#undef TFR
  o0 = x0; o1 = x1;
}

// jax.random.randint element e with pre-split subkeys k1=(a,b), k2=(c,d)
__device__ __forceinline__ unsigned jrand(unsigned a, unsigned b, unsigned c,
                                          unsigned d, unsigned e, unsigned span) {
  unsigned x0, x1, y0, y1;
  tf2x32(a, b, 0u, e, x0, x1);
  unsigned hi = x0 ^ x1;
  tf2x32(c, d, 0u, e, y0, y1);
  unsigned lo = y0 ^ y1;
  unsigned mult = 65536u % span;
  mult = (mult * mult) % span;
  return ((hi % span) * mult + (lo % span)) % span;
}

// ---------------- init / BFS ----------------
__global__ void k_zero16(uint4 *p, int n16) {
  int i = blockIdx.x * blockDim.x + threadIdx.x;
  if (i < n16) p[i] = make_uint4(0u, 0u, 0u, 0u);
}
__global__ void k_seed_samp(const int *seeds, int ns, unsigned char *cur,
                            unsigned char *mask_bfs,
                            unsigned a, unsigned b, unsigned c, unsigned d) {
  int i = blockIdx.x * blockDim.x + threadIdx.x;
  if (i < ns) { int s = seeds[i]; cur[s] = 1; mask_bfs[s] = 1; }
  if (i < SAMPN) {
    unsigned idx = jrand(a, b, c, d, (unsigned)i, (unsigned)NN);
    mask_bfs[idx] = 1;
  }
}
__global__ void k_level0(const int *rows, const int *cols, int E,
                         const unsigned char *cur, unsigned char *alive,
                         unsigned char *touched, unsigned char *mask_bfs) {
  int e = blockIdx.x * blockDim.x + threadIdx.x;
  if (e >= E) return;
  int r = rows[e], c = cols[e];
  if (cur[r] | cur[c]) {
    alive[e] = 0;
    touched[r] = 1; touched[c] = 1;
    mask_bfs[r] = 1; mask_bfs[c] = 1;
  } else alive[e] = 1;
}
__global__ void k_level1_deg(const int *rows, const int *cols, int E,
                             const unsigned char *touched, unsigned char *alive,
                             int *deg) {
  int e = blockIdx.x * blockDim.x + threadIdx.x;
  if (e >= E) return;
  if (alive[e]) {
    int r = rows[e];
    if (touched[r] | touched[cols[e]]) alive[e] = 0;
    else atomicAdd(&deg[r], 1);
  }
}

// ---------------- mask compaction (ushort indices) ----------------
__global__ __launch_bounds__(1024) void k_scan_mask(const unsigned char *flags,
                                                    unsigned short *mask_idx,
                                                    int *tem_num) {
  __shared__ int wsum[16];
  const unsigned *f = (const unsigned *)flags; // 10000 uints
  int tid = threadIdx.x, lane = tid & 63, wid = tid >> 6;
  int base = tid * 10;
  unsigned u[10];
  int cnt = 0;
  for (int j = 0; j < 10; j++) {
    int i = base + j;
    u[j] = (i < 10000) ? f[i] : 0u;
    cnt += __popc(u[j]);
  }
  int x = cnt;
  for (int d = 1; d < 64; d <<= 1) {
    int y = __shfl_up(x, d, 64);
    if (lane >= d) x += y;
  }
  if (lane == 63) wsum[wid] = x;
  __syncthreads();
  if (wid == 0) {
    int v = (lane < 16) ? wsum[lane] : 0;
    int y = v;
    for (int d = 1; d < 16; d <<= 1) {
      int z = __shfl_up(y, d, 64);
      if (lane >= d) y += z;
    }
    if (lane < 16) wsum[lane] = y - v;
  }
  __syncthreads();
  int off = wsum[wid] + (x - cnt);
  for (int j = 0; j < 10; j++) {
    int i = base + j;
    unsigned v = u[j];
    while (v) {
      int byte = (__ffs(v) - 1) >> 3;
      v &= v - 1;
      mask_idx[off++] = (unsigned short)(i * 4 + byte);
    }
  }
  if (tid == 1023) *tem_num = off;
}

// ---------------- binned append (tem + alive + self) + fused encoder ----------
__global__ __launch_bounds__(256) void k_append(
    const int *rows, const int *cols, const unsigned char *alive,
    const int *deg, const unsigned short *mask_idx, const int *tem_num,
    int *cursors, unsigned *bucketmem, float *out,
    unsigned ra, unsigned rb, unsigned rc, unsigned rd,
    unsigned ca, unsigned cb, unsigned cc, unsigned cd, int E) {
  __shared__ unsigned sorted[SCAP];     // 34 KB
  __shared__ int cnt[NB];               // 4 KB
  __shared__ unsigned short ofs[NB];    // 2 KB
  __shared__ int ntot_s;
  int tid = threadIdx.x, lane = tid & 63, wid = tid >> 6;
  int e0 = blockIdx.x * EPB;
  int i0 = blockIdx.x * SELFPB;         // self-node range
  int i1 = i0 + SELFPB; if (i1 > NN) i1 = NN;
  unsigned span = (unsigned)*tem_num;
  const unsigned NOPE = 0xFFFFFFFFu;

  unsigned tval[NE], aval[NE];

  for (int i = tid; i < NB; i += 256) cnt[i] = 0;
  __syncthreads();
  // pass A: draw + gather once, count, cache in registers; fused encoder out
#pragma unroll
  for (int k = 0; k < NE; k++) {
    int e = e0 + k * 256 + tid;
    if (e < E) {
      unsigned iR = jrand(ra, rb, rc, rd, (unsigned)e, span);
      unsigned iC = jrand(ca, cb, cc, cd, (unsigned)e, span);
      unsigned tr = (unsigned)mask_idx[iR], tc = (unsigned)mask_idx[iC];
      tval[k] = (tr << 16) | tc;
      atomicAdd(&cnt[tr / RPB], 1);
      atomicAdd(&cnt[tc / RPB], 1);
      int r = rows[e], c = cols[e];
      float v = 0.0f;
      if (alive[e]) {
        aval[k] = ((unsigned)r << 16) | (unsigned)c;
        atomicAdd(&cnt[(unsigned)r / RPB], 1);
        float xr = (float)deg[r] + 1e-12f;
        float xc = (float)deg[c] + 1e-12f;
        float dr = (float)(1.0 / sqrt((double)xr));
        float dc = (float)(1.0 / sqrt((double)xc));
        v = dr * dc;
      } else aval[k] = NOPE;
      out[e] = (float)r;
      out[E + e] = (float)c;
      out[2 * E + e] = v;
    } else { tval[k] = NOPE; aval[k] = NOPE; }
  }
  for (int i = i0 + tid; i < i1; i += 256) atomicAdd(&cnt[i / RPB], 1);
  __syncthreads();
  // exclusive scan of cnt[1024] by wave 0 -> ofs (ushort)
  if (wid == 0) {
    int carry = 0;
    for (int c8 = 0; c8 < NB / 64; c8++) {
      int v = cnt[c8 * 64 + lane];
      int x = v;
      for (int d = 1; d < 64; d <<= 1) {
        int y = __shfl_up(x, d, 64);
        if (lane >= d) x += y;
      }
      ofs[c8 * 64 + lane] = (unsigned short)(carry + x - v);
      carry += __shfl(x, 63, 64);
    }
    if (lane == 0) ntot_s = carry;
  }
  __syncthreads();
  for (int i = tid; i < NB; i += 256) cnt[i] = ofs[i];
  __syncthreads();
  // pass B: scatter from registers (+ self)
#pragma unroll
  for (int k = 0; k < NE; k++) {
    unsigned v = tval[k];
    if (v != NOPE) {
      unsigned tr = v >> 16, tc = v & 0xFFFFu;
      int p1 = atomicAdd(&cnt[tr / RPB], 1);
      sorted[p1] = v;
      int p2 = atomicAdd(&cnt[tc / RPB], 1);
      sorted[p2] = (tc << 16) | tr;
      unsigned a = aval[k];
      if (a != NOPE) {
        int p3 = atomicAdd(&cnt[(a >> 16) / RPB], 1);
        sorted[p3] = a;
      }
    }
  }
  for (int i = i0 + tid; i < i1; i += 256) {
    int p = atomicAdd(&cnt[i / RPB], 1);
    sorted[p] = ((unsigned)i << 16) | (unsigned)i;
  }
  __syncthreads();
  // reserve global space: one atomicAdd per bucket per block
  int ntot = ntot_s;
  for (int b = tid; b < NB; b += 256) {
    int end = (b < NB - 1) ? (int)ofs[b + 1] : ntot;
    int len = end - (int)ofs[b];
    cnt[b] = len ? atomicAdd(&cursors[b * CURSTRIDE], len) : 0;
  }
  __syncthreads();
  // coalesced flush (store local row id in high 16)
  for (int j = tid; j < ntot; j += 256) {
    unsigned item = sorted[j];
    unsigned r = item >> 16;
    unsigned b = r / RPB;
    unsigned lr = r - b * RPB;
    int idx = cnt[b] + (j - (int)ofs[b]);
    if (idx < CAP) bucketmem[b * CAP + idx] = (lr << 16) | (item & 0xFFFFu);
  }
}

// ---------------- dedup: wave-per-row + summary bitmap (single read) --------
__global__ __launch_bounds__(256) void k_dedup(unsigned *bucketmem,
                                               const int *cursors, int *uniq_cnt) {
  int b = blockIdx.x;
  int rowbase = b * RPB;
  if (rowbase >= NN) { if (threadIdx.x == 0) uniq_cnt[b] = 0; return; }

  __shared__ unsigned short arr[CAP];  // 16 KB
  __shared__ int cnt[RPB];
  __shared__ int rowend[RPB];
  __shared__ int curs[RPB];
  __shared__ int rowoff[RPB];
  __shared__ unsigned bm[4][WORDS];    // 20 KB wave-private bitmaps
  __shared__ unsigned sm[4][SWORDS];

  int tid = threadIdx.x, lane = tid & 63, wid = tid >> 6;
  int n = cursors[b * CURSTRIDE]; if (n > CAP) n = CAP;
  const unsigned *src = bucketmem + (size_t)b * CAP;

  for (int i = tid; i < RPB; i += 256) cnt[i] = 0;
  __syncthreads();
  for (int j = tid; j < n; j += 256) atomicAdd(&cnt[src[j] >> 16], 1);
  __syncthreads();
  if (tid == 0) {
    int s = 0;
    for (int r = 0; r < RPB; r++) { curs[r] = s; s += cnt[r]; rowend[r] = s; }
  }
  __syncthreads();
  for (int j = tid; j < n; j += 256) {
    unsigned v = src[j];
    int p = atomicAdd(&curs[v >> 16], 1);
    arr[p] = (unsigned short)v;
  }
  for (int w = lane; w < WORDS; w += 64) bm[wid][w] = 0u;
  if (lane < SWORDS) sm[wid][lane] = 0u;
  __syncthreads();

  for (int r = wid; r < RPB; r += 4) {
    int s1 = rowend[r], s0 = s1 - cnt[r];
    for (int j = s0 + lane; j < s1; j += 64) {
      unsigned c = arr[j];
      atomicOr(&bm[wid][c >> 5], 1u << (c & 31));
      atomicOr(&sm[wid][c >> 10], 1u << ((c >> 5) & 31));
    }
    unsigned s = (lane < SWORDS) ? sm[wid][lane] : 0u;
    int m = 0;
    unsigned t = s;
    while (t) {
      int w = (lane << 5) + (__ffs(t) - 1);
      t &= t - 1;
      m += __popc(bm[wid][w]);
    }
    int x = m;
    for (int d = 1; d < 64; d <<= 1) {
      int y = __shfl_up(x, d, 64);
      if (lane >= d) x += y;
    }
    int u = __shfl(x, 63, 64);
    int pos = s0 + (x - m);
    t = s;
    while (t) {
      int w = (lane << 5) + (__ffs(t) - 1);
      t &= t - 1;
      unsigned mm = bm[wid][w];
      bm[wid][w] = 0u;
      while (mm) {
        int bit = __ffs(mm) - 1;
        mm &= mm - 1;
        arr[pos++] = (unsigned short)((w << 5) + bit);
      }
    }
    if (lane < SWORDS) sm[wid][lane] = 0u;
    if (lane == 0) cnt[r] = u;
  }
  __syncthreads();
  if (tid == 0) {
    int s = 0;
    for (int r = 0; r < RPB; r++) { rowoff[r] = s; s += cnt[r]; }
    uniq_cnt[b] = s;
  }
  __syncthreads();
  // write uniques as packed (row<<16)|col — ascending == hash order
  unsigned *dst = bucketmem + (size_t)b * CAP;
  for (int r = wid; r < RPB; r += 4) {
    int s0 = r ? rowend[r - 1] : 0;
    int u = cnt[r], o = rowoff[r];
    unsigned rowpack = (unsigned)(rowbase + r) << 16;
    for (int j = lane; j < u; j += 64)
      dst[o + j] = rowpack | (unsigned)arr[s0 + j];
  }
}

// ---------------- emit (fused offset-reduction + diag) ----------------
__global__ __launch_bounds__(256) void k_emit(const unsigned *bucketmem,
                                              const int *uniq_cnt, float *out,
                                              int E, int U) {
  __shared__ int part[4];
  int b = blockIdx.x;
  int tid = threadIdx.x, lane = tid & 63, wid = tid >> 6;
  // ob = sum of uniq_cnt[0..b) via masked butterfly reduction
  int acc = 0;
  for (int i = tid; i < NB; i += 256)
    if (i < b) acc += uniq_cnt[i];
  for (int d = 1; d < 64; d <<= 1) acc += __shfl_xor(acc, d, 64);
  if (lane == 0) part[wid] = acc;
  __syncthreads();
  int ob = part[0] + part[1] + part[2] + part[3];
  int ub = uniq_cnt[b];
  const unsigned *src = bucketmem + (size_t)b * CAP;
  int base3 = 3 * E;
  for (int j = tid; j < ub; j += 256) {
    unsigned h = src[j];
    unsigned r = h >> 16;
    unsigned c = h & 0xFFFFu;
    int idx = ob + j;
    if (idx < U) {
      out[base3 + idx] = (float)r;
      out[base3 + U + idx] = (float)c;
      out[base3 + 2 * U + idx] = 1.0f;
    }
  }
  if (b == NB - 1 && tid == 0) {
    int C = ob + ub;
    if (C != U) {
      int d = C - U; if (d < 0) d = -d; if (d > 60000) d = 60000;
      out[base3] = (float)(300000 + d); // sentinel (should never fire)
    }
  }
}

// ---------------- launch ----------------
extern "C" void kernel_launch(void *const *d_in, const int *in_sizes, int n_in,
                              void *d_out, int out_size, void *d_ws,
                              size_t ws_size, hipStream_t stream) {
  const int *rows = (const int *)d_in[0];
  const int *cols = (const int *)d_in[1];
  const int *seeds = (const int *)d_in[3];
  const int E = in_sizes[0];
  const int ns = in_sizes[3];
  float *out = (float *)d_out;
  const int U = (out_size - 3 * E) / 3;

  // ---- workspace carve: zeroed region first, rest after ----
  int *I = (int *)d_ws;
  int *deg = I;      I += NN;               // zeroed
  int *cursors = I;  I += NB * CURSTRIDE;   // zeroed
  int *uniq_cnt = I; I += NB;               // zeroed
  unsigned char *cur = (unsigned char *)I;  // 3*NN bytes zeroed
  unsigned char *touched = cur + NN;
  unsigned char *mask_bfs = touched + NN;
  size_t zero_bytes = (size_t)((char *)(mask_bfs + NN) - (char *)deg);
  int *J = (int *)(mask_bfs + NN);
  int *tem_num = J;  J += 1;
  J += 1; // pad to 8B
  unsigned short *mask_idx = (unsigned short *)J;
  J += NN / 2; // 40000 ushorts = 20000 ints
  unsigned *bucketmem = (unsigned *)J; J += (size_t)NB * CAP; // 32 MB
  unsigned char *alive = (unsigned char *)J; // E bytes (fully written)

  // ---- host key derivation (v0): key(1)=(0,1); split(3); randint split(2) ----
  unsigned F[3][2];
  tf2x32(0u, 1u, 0u, 0u, F[0][0], F[0][1]); // kS
  tf2x32(0u, 1u, 0u, 1u, F[1][0], F[1][1]); // kR
  tf2x32(0u, 1u, 0u, 2u, F[2][0], F[2][1]); // kC
  unsigned K[3][4];
  for (int s = 0; s < 3; s++) {
    tf2x32(F[s][0], F[s][1], 0u, 0u, K[s][0], K[s][1]); // k1 (higher bits)
    tf2x32(F[s][0], F[s][1], 0u, 1u, K[s][2], K[s][3]); // k2 (lower bits)
  }

  dim3 b(256);
  int gE = (E + 255) / 256;
  int gSS = (SAMPN + 255) / 256; // covers ns=2000 too
  int gT = (E + EPB - 1) / EPB;  // 910; also covers self nodes (910*44>=NN)
  int n16 = (int)(zero_bytes / 16);

  k_zero16<<<(n16 + 255) / 256, b, 0, stream>>>((uint4 *)deg, n16);
  k_seed_samp<<<gSS, b, 0, stream>>>(seeds, ns, cur, mask_bfs,
                                     K[0][0], K[0][1], K[0][2], K[0][3]);
  k_level0<<<gE, b, 0, stream>>>(rows, cols, E, cur, alive, touched, mask_bfs);
  k_level1_deg<<<gE, b, 0, stream>>>(rows, cols, E, touched, alive, deg);
  k_scan_mask<<<1, 1024, 0, stream>>>(mask_bfs, mask_idx, tem_num);
  k_append<<<gT, b, 0, stream>>>(rows, cols, alive, deg, mask_idx, tem_num,
                                 cursors, bucketmem, out,
                                 K[1][0], K[1][1], K[1][2], K[1][3],
                                 K[2][0], K[2][1], K[2][2], K[2][3], E);
  k_dedup<<<NB, b, 0, stream>>>(bucketmem, cursors, uniq_cnt);
  k_emit<<<NB, b, 0, stream>>>(bucketmem, uniq_cnt, out, E, U);
}